// Round 10
// baseline (589.185 us; speedup 1.0000x reference)
//
#include <hip/hip_runtime.h>
#include <hip/hip_fp16.h>

#define N_NODES_C 100000
#define N_EDGES_C 3200000
#define IN_F_C 10
#define HID_C 64
#define N_CLS_C 10
#define NEG_SLOPE_C 0.01f

#define NBUCK 98        // ceil(100000/1024); bucket = dst >> 10
#define BCAP  36864     // mean 32768, sigma ~180 -> +22 sigma headroom
#define TILE  2048      // edges per block in k_bucket
#define NRANGE 4        // src ranges of 25000 nodes (3.2 MB hs slice, fits 4MB XCD L2)
#define NDW   13        // dsts per wave in persistent gather (8192 waves * 13 >= 100000)
#define PGB   2048      // persistent gather blocks = 256 CU * 8

// ---------------- pass 1: bucket partition (unchanged, proven) ----------------
__global__ __launch_bounds__(256) void k_bucket(const int* __restrict__ src,
                                                const int* __restrict__ dst,
                                                int* __restrict__ bcur,
                                                int* __restrict__ pairs, int E) {
    __shared__ int lcnt[NBUCK];
    __shared__ int gbase[NBUCK];
    const int t = threadIdx.x;
    for (int i = t; i < NBUCK; i += 256) lcnt[i] = 0;
    __syncthreads();
    const int base = blockIdx.x * TILE;
    int p[8], r[8], nb[8];
#pragma unroll
    for (int i = 0; i < 8; ++i) {
        int e = base + t + i * 256;
        if (e < E) {
            int s = src[e], d = dst[e];
            int b = d >> 10;
            nb[i] = b;
            p[i] = (s << 10) | (d & 1023);
            r[i] = atomicAdd(&lcnt[b], 1);
        }
    }
    __syncthreads();
    for (int i = t; i < NBUCK; i += 256)
        gbase[i] = lcnt[i] ? atomicAdd(&bcur[i], lcnt[i]) : 0;
    __syncthreads();
#pragma unroll
    for (int i = 0; i < 8; ++i) {
        int e = base + t + i * 256;
        if (e < E) {
            int pos = gbase[nb[i]] + r[i];
            if (pos < BCAP) pairs[nb[i] * BCAP + pos] = p[i];
        }
    }
}

// ---------------- tiny scan of 98 bucket sizes ----------------
__global__ __launch_bounds__(128) void k_bscan(const int* __restrict__ bcur,
                                               int* __restrict__ bOff, int nbk) {
    __shared__ int s[128];
    int t = threadIdx.x;
    int v = (t < nbk) ? bcur[t] : 0;
    s[t] = v;
    __syncthreads();
    for (int off = 1; off < 128; off <<= 1) {
        int u = (t >= off) ? s[t - off] : 0;
        __syncthreads();
        s[t] += u;
        __syncthreads();
    }
    if (t < nbk) bOff[t] = s[t] - v;
}

// ---------------- pass 2: per-bucket build with RANGE-GROUPED rows ----------------
// col rows ordered by src-range; rp2[(d<<2)+r] = start of (d, r); rp2[4N] = E
__global__ __launch_bounds__(1024) void k_build(const int* __restrict__ pairs,
                                                const int* __restrict__ bcur,
                                                const int* __restrict__ bOff,
                                                int* __restrict__ rp2,
                                                float* __restrict__ dinv,
                                                int* __restrict__ col) {
    __shared__ int hist[1024];
    __shared__ int sm[1024];
    const int b = blockIdx.x;
    const int t = threadIdx.x;
    const int nE = min(bcur[b], BCAP);
    const int base = bOff[b];
    const int* pp = pairs + b * BCAP;

    hist[t] = 0;
    __syncthreads();
    for (int i = t; i < nE; i += 1024) atomicAdd(&hist[pp[i] & 1023], 1);
    __syncthreads();
    int c = hist[t];
    sm[t] = c;
    __syncthreads();
    for (int off = 1; off < 1024; off <<= 1) {
        int u = (t >= off) ? sm[t - off] : 0;
        __syncthreads();
        sm[t] += u;
        __syncthreads();
    }
    int rp = base + sm[t] - c;
    int gnode = (b << 10) + t;
    bool valid = gnode < N_NODES_C;
    if (valid) {
        dinv[gnode] = rsqrtf((float)(c + 1));
        if (gnode == N_NODES_C - 1) rp2[4 * N_NODES_C] = rp + c;
    }
    __syncthreads();
    sm[t] = rp;                              // absolute cursor per local node
    for (int r = 0; r < NRANGE; ++r) {
        __syncthreads();
        if (valid) rp2[(gnode << 2) | r] = sm[t];   // snapshot = start of (node, r)
        __syncthreads();
        for (int i = t; i < nE; i += 1024) {
            int p = pp[i];
            int s = p >> 10;
            if (s / 25000 == r) {
                int idx = atomicAdd(&sm[p & 1023], 1);
                col[idx] = s;
            }
        }
    }
}

// ---------------- layer-1 transform: hs = (x @ W1) * dinv (unchanged) ----------------
__global__ __launch_bounds__(256) void k_mm0(const float* __restrict__ x,
                                             const float* __restrict__ W,
                                             const float* __restrict__ dinv,
                                             __half* __restrict__ hs, int n) {
    __shared__ float4 W4[IN_F_C * 16];
    const int t = threadIdx.x;
    for (int i = t; i < IN_F_C * 16; i += 256) {
        int k = i >> 4, f4 = i & 15;
        W4[i] = ((const float4*)(W + k * HID_C))[f4];
    }
    __syncthreads();
    int idx = blockIdx.x * 256 + t;
    if (idx >= n * 16) return;
    int nn = idx >> 4, f4 = idx & 15;
    const float* row = x + nn * IN_F_C;
    float4 acc = make_float4(0.f, 0.f, 0.f, 0.f);
#pragma unroll
    for (int k = 0; k < IN_F_C; ++k) {
        float xv = row[k];
        float4 w = W4[k * 16 + f4];
        acc.x += xv * w.x; acc.y += xv * w.y; acc.z += xv * w.z; acc.w += xv * w.w;
    }
    float di = dinv[nn];
    ((__half2*)hs)[(nn << 5) + 2 * f4]     = __floats2half2_rn(acc.x * di, acc.y * di);
    ((__half2*)hs)[(nn << 5) + 2 * f4 + 1] = __floats2half2_rn(acc.z * di, acc.w * di);
}

// ---------------- persistent range-swept gather ----------------
// All 8192 waves sweep src-ranges together; fp32 partials parked in LDS between ranges.
__global__ __launch_bounds__(256, 8) void k_pg(const int* __restrict__ rp2,
                                               const int* __restrict__ col,
                                               const __half2* __restrict__ hs,   // [n][32]
                                               const float* __restrict__ dinv,
                                               const float* __restrict__ bias,
                                               __half2* __restrict__ act,        // [n][32]
                                               int n) {
    __shared__ float2 accL[4][NDW][32];
    const int t = threadIdx.x;
    const int lane = t & 63;
    const int wid  = t >> 6;
    const int half = lane >> 5;
    const int fl   = lane & 31;
    const int wave = (blockIdx.x << 2) + wid;
    const int base = wave * NDW;
    if (base >= n) return;

    for (int r = 0; r < NRANGE; ++r) {
        for (int j = 0; j < NDW; ++j) {
            int d = base + j;
            if (d >= n) break;
            int beg = rp2[(d << 2) + r];
            int end = rp2[(d << 2) + r + 1];
            float2 acc = make_float2(0.f, 0.f);
            int e = beg;
            for (; e + 7 < end; e += 8) {
                int i0 = e + half, i1 = e + 2 + half, i2 = e + 4 + half, i3 = e + 6 + half;
                int s0 = col[i0], s1 = col[i1], s2 = col[i2], s3 = col[i3];
                float2 v0 = __half22float2(hs[(s0 << 5) + fl]);
                float2 v1 = __half22float2(hs[(s1 << 5) + fl]);
                float2 v2 = __half22float2(hs[(s2 << 5) + fl]);
                float2 v3 = __half22float2(hs[(s3 << 5) + fl]);
                acc.x += v0.x + v1.x + v2.x + v3.x;
                acc.y += v0.y + v1.y + v2.y + v3.y;
            }
            if (e + 3 < end) {
                int i0 = e + half, i1 = e + 2 + half;
                int s0 = col[i0], s1 = col[i1];
                float2 v0 = __half22float2(hs[(s0 << 5) + fl]);
                float2 v1 = __half22float2(hs[(s1 << 5) + fl]);
                acc.x += v0.x + v1.x;
                acc.y += v0.y + v1.y;
                e += 4;
            }
            for (; e < end; e += 2) {
                int i = e + half;
                if (i < end) {
                    float2 v = __half22float2(hs[(col[i] << 5) + fl]);
                    acc.x += v.x; acc.y += v.y;
                }
            }
            // combine halves, park in LDS (half0 owns the slot)
            acc.x += __shfl_xor(acc.x, 32, 64);
            acc.y += __shfl_xor(acc.y, 32, 64);
            if (!half) {
                if (r == 0) {
                    accL[wid][j][fl] = acc;
                } else {
                    float2 o = accL[wid][j][fl];
                    o.x += acc.x; o.y += acc.y;
                    accL[wid][j][fl] = o;
                }
            }
        }
    }
    // epilogue: self-loop + scale + bias + leaky-relu, fp16 act out
    for (int j = 0; j < NDW; ++j) {
        int d = base + j;
        if (d >= n) break;
        if (!half) {
            float2 a = accL[wid][j][fl];
            float2 sv = __half22float2(hs[(d << 5) + fl]);
            float di = dinv[d];
            float2 bb = ((const float2*)bias)[fl];
            float vx = (a.x + sv.x) * di + bb.x;
            float vy = (a.y + sv.y) * di + bb.y;
            vx = vx > 0.f ? vx : NEG_SLOPE_C * vx;
            vy = vy > 0.f ? vy : NEG_SLOPE_C * vy;
            act[(d << 5) + fl] = __floats2half2_rn(vx, vy);
        }
    }
}

// ---------------- dense transform: hs[n,f'] = (act[n,:] @ W)[f'] * dinv[n], coalesced ----------------
__global__ __launch_bounds__(256) void k_xform(const __half* __restrict__ act,
                                               const float* __restrict__ W,   // [64][64]
                                               const float* __restrict__ dinv,
                                               __half* __restrict__ hs, int n) {
    __shared__ uint4 aLDS[64][8];        // 64 node rows x 128B
    __shared__ __half2 Wh2[32 * 64];     // W k-pairs fp16: Wh2[k2*64+f]
    const int t = threadIdx.x;
    const int base = blockIdx.x * 64;
    // stage W (fp32 -> fp16 pairs)
    for (int i = t; i < 32 * 64; i += 256) {
        int k2 = i >> 6, f = i & 63;
        Wh2[i] = __floats2half2_rn(W[(2 * k2) * HID_C + f], W[(2 * k2 + 1) * HID_C + f]);
    }
    // stage act rows, fully coalesced uint4
    const uint4* aG = (const uint4*)act;             // 8 uint4 per row
    for (int i = t; i < 64 * 8; i += 256) {
        int row = i >> 3, q = i & 7;
        aLDS[row][q] = aG[(size_t)(base + row) * 8 + q];   // OOB rows read scratch (guarded on write)
    }
    __syncthreads();

    const int lane = t & 63;
    const int wid  = t >> 6;
#pragma unroll 4
    for (int ii = 0; ii < 16; ++ii) {
        int nn = wid * 16 + ii;
        int node = base + nn;
        const __half2* aRow = (const __half2*)&aLDS[nn][0];
        float s = 0.f;
#pragma unroll
        for (int k2 = 0; k2 < 32; ++k2) {
            float2 af = __half22float2(aRow[k2]);          // broadcast
            float2 wf = __half22float2(Wh2[(k2 << 6) + lane]);
            s += af.x * wf.x + af.y * wf.y;
        }
        if (node < n) hs[((size_t)node << 6) + lane] = __float2half(s * dinv[node]);
    }
}

// ---------------- final FC: out = act @ Wfc + bfc, coalesced ----------------
__global__ __launch_bounds__(256) void k_fc(const __half* __restrict__ act,
                                            const float* __restrict__ W,   // [64][10]
                                            const float* __restrict__ b,
                                            float* __restrict__ out, int n) {
    __shared__ uint4 aLDS[64][8];
    __shared__ float2 Wf2[32 * N_CLS_C];  // k-pairs: Wf2[k2*10+c]
    __shared__ float bL[N_CLS_C];
    const int t = threadIdx.x;
    const int base = blockIdx.x * 64;
    for (int i = t; i < 32 * N_CLS_C; i += 256) {
        int k2 = i / N_CLS_C, c = i - k2 * N_CLS_C;
        Wf2[i] = make_float2(W[(2 * k2) * N_CLS_C + c], W[(2 * k2 + 1) * N_CLS_C + c]);
    }
    if (t < N_CLS_C) bL[t] = b[t];
    const uint4* aG = (const uint4*)act;
    for (int i = t; i < 64 * 8; i += 256) {
        int row = i >> 3, q = i & 7;
        aLDS[row][q] = aG[(size_t)(base + row) * 8 + q];
    }
    __syncthreads();

    const int lane = t & 63;
    const int wid  = t >> 6;
    if (lane >= N_CLS_C) return;
    for (int ii = 0; ii < 16; ++ii) {
        int nn = wid * 16 + ii;
        int node = base + nn;
        const __half2* aRow = (const __half2*)&aLDS[nn][0];
        float s = bL[lane];
#pragma unroll
        for (int k2 = 0; k2 < 32; ++k2) {
            float2 af = __half22float2(aRow[k2]);          // broadcast
            float2 wf = Wf2[k2 * N_CLS_C + lane];
            s += af.x * wf.x + af.y * wf.y;
        }
        if (node < n) out[(size_t)node * N_CLS_C + lane] = s;
    }
}

extern "C" void kernel_launch(void* const* d_in, const int* in_sizes, int n_in,
                              void* d_out, int out_size, void* d_ws, size_t ws_size,
                              hipStream_t stream) {
    const float* x   = (const float*)d_in[0];
    const int*   ei  = (const int*)d_in[1];
    const float* W1  = (const float*)d_in[2];
    const float* b1  = (const float*)d_in[3];
    const float* W2  = (const float*)d_in[4];
    const float* b2  = (const float*)d_in[5];
    const float* W3  = (const float*)d_in[6];
    const float* b3  = (const float*)d_in[7];
    const float* Wfc = (const float*)d_in[8];
    const float* bfc = (const float*)d_in[9];
    float* out = (float*)d_out;

    const int N = N_NODES_C;
    const int E = N_EDGES_C;
    const int* src = ei;
    const int* dst = ei + E;

    // workspace carve-up (16B aligned)
    float*  dinv = (float*)d_ws;                       // N
    int*    bcur = (int*)(dinv + N);                   // 128 (zeroed)
    int*    bOff = bcur + 128;                         // 128
    int*    rp2  = bOff + 128;                         // 4N+16
    int*    col  = rp2 + 4 * N + 16;                   // E
    int*    pairs = col + E;                           // NBUCK*BCAP ints (14.45MB)
    __half* hsA  = (__half*)pairs;                     // N*64 halves (aliases pairs; pairs dead after k_build)
    __half* hsB  = (__half*)(pairs + (size_t)NBUCK * BCAP);      // N*64 halves
    __half* act  = hsB + (size_t)N * HID_C;            // N*64 halves

    int gM0 = (N * 16 + 255) / 256;
    int gBK = (E + TILE - 1) / TILE;
    int gXF = (N + 63) / 64;

    // ---- CSR build (+ dinv), range-grouped rows ----
    hipMemsetAsync(bcur, 0, 128 * sizeof(int), stream);
    k_bucket<<<gBK, 256, 0, stream>>>(src, dst, bcur, pairs, E);
    k_bscan<<<1, 128, 0, stream>>>(bcur, bOff, NBUCK);
    k_build<<<NBUCK, 1024, 0, stream>>>(pairs, bcur, bOff, rp2, dinv, col);

    // ---- layer 1 ----
    k_mm0<<<gM0, 256, 0, stream>>>(x, W1, dinv, hsA, N);
    k_pg<<<PGB, 256, 0, stream>>>(rp2, col, (const __half2*)hsA, dinv, b1, (__half2*)act, N);
    // ---- layer 2 ----
    k_xform<<<gXF, 256, 0, stream>>>(act, W2, dinv, hsB, N);
    k_pg<<<PGB, 256, 0, stream>>>(rp2, col, (const __half2*)hsB, dinv, b2, (__half2*)act, N);
    // ---- layer 3 ----
    k_xform<<<gXF, 256, 0, stream>>>(act, W3, dinv, hsA, N);
    k_pg<<<PGB, 256, 0, stream>>>(rp2, col, (const __half2*)hsA, dinv, b3, (__half2*)act, N);
    // ---- final FC ----
    k_fc<<<gXF, 256, 0, stream>>>(act, Wfc, bfc, out, N);
}